// Round 1
// 242.778 us; speedup vs baseline: 1.1304x; 1.1304x over previous
//
#include <hip/hip_runtime.h>
#include <math.h>

#define N_NODES 100000
#define D_FEAT  256
#define TOP_K   50000
#define NBINS   65536
#define NCHUNK  64          // NBINS / 1024 chunks for the parallel scan
#define CUTPOS  (N_NODES - TOP_K)
#define ROWSTRIDE 260   // 256 + 4 pad: bank = (4g + l + 8i) % 32 -> 2-way = free

// Workspace layout (byte offsets, all 16B-aligned):
//         0 : s32      float[N_NODES]   (400,000)  f32 scores (OpenBLAS+numpy emulation)
//   400,000 : ss       float[N_NODES]   (400,000)  bucket-sorted scores
//   800,000 : si       int[N_NODES]     (400,000)  bucket-sorted node ids
// 1,200,000 : hist     int[NBINS]       (262,144)  } zeroed together
// 1,462,144 : member   uchar[N_NODES]   (100,000)  } (362,144 B memset)
// 1,562,144 : offs     int[NBINS]       (262,144)  chunk-LOCAL exclusive offsets
// 1,824,288 : cursor   int[NBINS]       (262,144)  scatter cursors (init = offs)
// 2,086,432 : chunkSum int[NCHUNK]      (256)      per-chunk totals

__device__ __forceinline__ int bucket_of(float s) {
    int b = (int)(s * 65536.0f);
    return min(max(b, 0), NBINS - 1);
}

// numpy SIMD float32 exp (FMA universal-intrinsics path) — bit-exact, verified R6.
__device__ __forceinline__ float np_expf(float x) {
    float q  = rintf(x * 1.44269504088896341f);
    float xr = fmaf(-q, 0.693359375f, x);
    xr       = fmaf(-q, -2.12194440e-4f, xr);
    float x2 = xr * xr;
    float p  = 1.9875691500E-4f;
    p = fmaf(p, xr, 1.3981999507E-3f);
    p = fmaf(p, xr, 8.3334519073E-3f);
    p = fmaf(p, xr, 4.1665795894E-2f);
    p = fmaf(p, xr, 1.6666665459E-1f);
    p = fmaf(p, xr, 5.0000001201E-1f);
    p = fmaf(p, x2, xr);
    p = p + 1.0f;
    return ldexpf(p, (int)q);
}

// OpenBLAS sgemv_t emulation, parallelized 8 lanes/node (R6 numerics, bit-exact):
// lane 8g+l runs chain l (k = i*8+l, i=0..31, serial fmaf) for node g of its wave;
// merge via shfl_xor 1,2,4 reproduces ((a0+a1)+(a2+a3))+((a4+a5)+(a6+a7)).
// Block = 256 thr = 4 waves = 32 nodes; rows staged to LDS coalesced.
// DO NOT TOUCH the numerics: bit-exact scores gate the top-k tie boundary.
__global__ void score_kernel(const float* __restrict__ h,
                             const float* __restrict__ W,
                             const float* __restrict__ bvec,
                             float* __restrict__ s32,
                             int* __restrict__ hist) {
    __shared__ float rows[32 * ROWSTRIDE];   // 33,280 B
    __shared__ float wl[256];
    int tid  = threadIdx.x;
    int wave = tid >> 6;
    int lane = tid & 63;
    int g    = lane >> 3;    // node within wave's 8
    int l    = lane & 7;     // chain id

    wl[tid] = W[tid];

    // stage this wave's 8 rows: one float4 per lane per row, coalesced 1KB
    int nodeBase = blockIdx.x * 32 + wave * 8;
#pragma unroll
    for (int r = 0; r < 8; ++r) {
        float4 v = ((const float4*)(h + (size_t)(nodeBase + r) * D_FEAT))[lane];
        *((float4*)&rows[(wave * 8 + r) * ROWSTRIDE + lane * 4]) = v;
    }
    __syncthreads();

    // W chain-slice into registers: wreg[i] = W[i*8 + l] (8-way LDS broadcast, free)
    float wreg[32];
#pragma unroll
    for (int i = 0; i < 32; ++i) wreg[i] = wl[i * 8 + l];

    // serial chain: acc = sum_{i} h[node][i*8+l] * W[i*8+l], strict fmaf order
    const float* myrow = &rows[(wave * 8 + g) * ROWSTRIDE];
    float acc = 0.0f;
#pragma unroll
    for (int i = 0; i < 32; ++i)
        acc = fmaf(myrow[i * 8 + l], wreg[i], acc);

    // vhaddps-style adjacent-pairwise merge tree (lane 8g+0 holds node g's z)
    float b01 = acc + __shfl_xor(acc, 1, 64);
    float b23 = b01 + __shfl_xor(b01, 2, 64);
    float z   = b23 + __shfl_xor(b23, 4, 64);

    z = z + bvec[0];
    float x = -z;
    float t = np_expf(x);
    float u = 1.0f + t;
    float s = 1.0f / u;                // IEEE f32 divide

    if (l == 0) {
        int node = nodeBase + g;
        s32[node] = s;
        atomicAdd(&hist[bucket_of(s)], 1);
    }
}

// Parallel chunk scan: 64 blocks x 256 threads, 4 consecutive bins per thread
// (int4 coalesced). Writes chunk-LOCAL exclusive offsets into offs+cursor and
// the per-chunk total into chunkSum. Global base = exclusive scan of chunkSum,
// recomputed in-register (64 ints, L2-broadcast) by each consumer block.
__global__ void scan_chunks_kernel(const int* __restrict__ hist,
                                   int* __restrict__ offs,
                                   int* __restrict__ cursor,
                                   int* __restrict__ chunkSum) {
    __shared__ int wsum[4];
    int tid  = threadIdx.x;
    int lane = tid & 63;
    int wid  = tid >> 6;
    int base = blockIdx.x * 1024 + tid * 4;

    int4 hv = *((const int4*)(hist + base));
    int e1 = hv.x;
    int e2 = hv.x + hv.y;
    int e3 = e2 + hv.z;
    int tot = e3 + hv.w;

    // wave-inclusive scan of per-thread totals
    int incl = tot;
#pragma unroll
    for (int d = 1; d < 64; d <<= 1) {
        int t = __shfl_up(incl, d, 64);
        if (lane >= d) incl += t;
    }
    if (lane == 63) wsum[wid] = incl;
    __syncthreads();
    int wbase = 0;
#pragma unroll
    for (int w = 0; w < 3; ++w)
        if (w < wid) wbase += wsum[w];

    int excl = wbase + (incl - tot);           // chunk-local exclusive base
    int4 ov = make_int4(excl, excl + e1, excl + e2, excl + e3);
    *((int4*)(offs + base))   = ov;
    *((int4*)(cursor + base)) = ov;
    if (tid == 255) chunkSum[blockIdx.x] = excl + tot;
}

// Wave-0 helper: exclusive scan of the 64 chunk totals into LDS.
__device__ __forceinline__ void build_base(const int* __restrict__ chunkSum,
                                           int* sbase, int tid) {
    if (tid < 64) {
        int v = chunkSum[tid];
        int inc = v;
#pragma unroll
        for (int d = 1; d < 64; d <<= 1) {
            int t = __shfl_up(inc, d, 64);
            if (tid >= d) inc += t;
        }
        sbase[tid] = inc - v;
    }
}

__global__ void scatter_kernel(const float* __restrict__ s32,
                               int* __restrict__ cursor,
                               const int* __restrict__ chunkSum,
                               float* __restrict__ ss,
                               int* __restrict__ si) {
    __shared__ int sbase[64];
    int tid = threadIdx.x;
    build_base(chunkSum, sbase, tid);
    __syncthreads();
    int i = blockIdx.x * 256 + tid;
    if (i >= N_NODES) return;
    float s = s32[i];
    int b = bucket_of(s);
    int pos = sbase[b >> 10] + atomicAdd(&cursor[b], 1);
    ss[pos] = s;
    si[pos] = i;
}

// One thread per bucket; insertion sort ascending by (s asc, idx desc)
// so reversed (descending) order is (s desc, idx asc) — lax.top_k tie rule.
// Buckets entirely below the top-k cut (e <= CUTPOS) are never read -> skip.
__global__ void bucket_sort_kernel(const int* __restrict__ offs,
                                   const int* __restrict__ chunkSum,
                                   float* __restrict__ ss,
                                   int* __restrict__ si) {
    __shared__ int sbase[65];
    int tid = threadIdx.x;
    build_base(chunkSum, sbase, tid);
    if (tid == 64) sbase[64] = N_NODES;
    __syncthreads();
    int b = blockIdx.x * 256 + tid;
    int s0 = sbase[b >> 10] + offs[b];
    int e  = (b == NBINS - 1) ? N_NODES : sbase[(b + 1) >> 10] + offs[b + 1];
    if (e <= CUTPOS || e - s0 < 2) return;
    for (int i = s0 + 1; i < e; ++i) {
        float ks = ss[i];
        int   ki = si[i];
        int j = i - 1;
        while (j >= s0) {
            float ps = ss[j];
            int   pi = si[j];
            bool gt = (ps > ks) || (ps == ks && pi < ki);
            if (!gt) break;
            ss[j + 1] = ps;
            si[j + 1] = pi;
            --j;
        }
        ss[j + 1] = ks;
        si[j + 1] = ki;
    }
}

// Fused emit+gather: block handles 4 output rows (1 wave each).
// Lane 0 writes member/out_ids; all lanes gather+scale the feature row.
__global__ void emit_gather_kernel(const float* __restrict__ h,
                                   const float* __restrict__ ss,
                                   const int* __restrict__ si,
                                   float* __restrict__ out_newh,
                                   float* __restrict__ out_ids,
                                   unsigned char* __restrict__ member) {
    int tid  = threadIdx.x;
    int row  = blockIdx.x * 4 + (tid >> 6);   // grid = TOP_K/4, TOP_K%4==0
    int lane = tid & 63;
    int p = N_NODES - 1 - row;
    int id  = si[p];      // same addr across wave -> single broadcast request
    float s = ss[p];
    if (lane == 0) {
        member[id]   = 1;
        out_ids[row] = (float)id;
    }
    const float4* hv = (const float4*)(h + (size_t)id * D_FEAT);
    float4 v = hv[lane];
    ((float4*)(out_newh + (size_t)row * D_FEAT))[lane] =
        make_float4(v.x * s, v.y * s, v.z * s, v.w * s);
}

// Edge mask with fused dtype detect (wave-0 ballot over first 64 hi-dwords)
// and int4 loads (2 edges per thread).
__global__ void edge_kernel(const int* __restrict__ ei,
                            const unsigned char* __restrict__ member,
                            float* __restrict__ out_mask,
                            int E) {
    __shared__ int sflag;
    int tid = threadIdx.x;
    if (tid < 64) {
        int v = ei[2 * tid + 1];
        unsigned long long m = __ballot(v == 0);
        if (tid == 0) sflag = (m == ~0ULL) ? 1 : 0;
    }
    __syncthreads();
    int flag = sflag;

    int k  = blockIdx.x * 256 + tid;   // edge-pair index
    int i0 = 2 * k;
    int i1 = i0 + 1;
    if (i0 >= E) return;

    int s0, d0, s1 = 0, d1 = 0;
    if (i1 < E) {
        if (flag) {                    // int64 storage: value in even dword
            int4 a  = ((const int4*)ei)[k];
            int4 bq = ((const int4*)(ei + 2 * (size_t)E))[k];
            s0 = a.x;  s1 = a.z;
            d0 = bq.x; d1 = bq.z;
        } else {                       // int32 storage
            int2 a  = ((const int2*)ei)[k];
            int2 bq = ((const int2*)(ei + (size_t)E))[k];
            s0 = a.x;  s1 = a.y;
            d0 = bq.x; d1 = bq.y;
        }
    } else {                           // odd-E tail (not hit for E=3.2M)
        if (flag) { s0 = ei[2 * i0]; d0 = ei[2 * ((size_t)E + i0)]; }
        else      { s0 = ei[i0];     d0 = ei[(size_t)E + i0]; }
    }

    bool ok0 = ((unsigned)s0 < (unsigned)N_NODES) &&
               ((unsigned)d0 < (unsigned)N_NODES) &&
               member[s0] && member[d0];
    out_mask[i0] = ok0 ? 1.0f : 0.0f;
    if (i1 < E) {
        bool ok1 = ((unsigned)s1 < (unsigned)N_NODES) &&
                   ((unsigned)d1 < (unsigned)N_NODES) &&
                   member[s1] && member[d1];
        out_mask[i1] = ok1 ? 1.0f : 0.0f;
    }
}

extern "C" void kernel_launch(void* const* d_in, const int* in_sizes, int n_in,
                              void* d_out, int out_size, void* d_ws, size_t ws_size,
                              hipStream_t stream) {
    const float* h  = (const float*)d_in[0];
    const float* W  = (const float*)d_in[1];
    const float* bv = (const float*)d_in[2];
    const int*   ei = (const int*)d_in[3];
    const int E = in_sizes[3] / 2;

    char* ws = (char*)d_ws;
    float*         s32      = (float*)(ws + 0);
    float*         ss       = (float*)(ws + 400000);
    int*           si       = (int*)(ws + 800000);
    int*           hist     = (int*)(ws + 1200000);
    unsigned char* member   = (unsigned char*)(ws + 1462144);
    int*           offs     = (int*)(ws + 1562144);
    int*           cursor   = (int*)(ws + 1824288);
    int*           chunkSum = (int*)(ws + 2086432);

    float* out      = (float*)d_out;
    float* out_newh = out;                                  // TOP_K * D_FEAT
    float* out_ids  = out + (size_t)TOP_K * D_FEAT;         // TOP_K
    float* out_mask = out + (size_t)TOP_K * D_FEAT + TOP_K; // E

    hipMemsetAsync(ws + 1200000, 0, 362144, stream);        // hist + member

    score_kernel<<<N_NODES / 32, 256, 0, stream>>>(h, W, bv, s32, hist);
    scan_chunks_kernel<<<NCHUNK, 256, 0, stream>>>(hist, offs, cursor, chunkSum);
    scatter_kernel<<<(N_NODES + 255) / 256, 256, 0, stream>>>(s32, cursor, chunkSum, ss, si);
    bucket_sort_kernel<<<NBINS / 256, 256, 0, stream>>>(offs, chunkSum, ss, si);
    emit_gather_kernel<<<TOP_K / 4, 256, 0, stream>>>(h, ss, si, out_newh, out_ids, member);
    edge_kernel<<<(E / 2 + 255) / 256, 256, 0, stream>>>(ei, member, out_mask, E);
}